// Round 1
// 596.386 us; speedup vs baseline: 1.0446x; 1.0446x over previous
//
#include <hip/hip_runtime.h>

#define BATCH 65536
#define DIM   256
#define CODES 1024
#define TAU   6e-3f

typedef short bf16x8 __attribute__((ext_vector_type(8)));
typedef float f32x4  __attribute__((ext_vector_type(4)));

__device__ inline unsigned short f2bf(float f) {
    unsigned u = __float_as_uint(f);
    u += 0x7FFFu + ((u >> 16) & 1u);
    return (unsigned short)(u >> 16);
}
__device__ inline float bf2f(unsigned short h) {
    return __uint_as_float(((unsigned)h) << 16);
}

// async global->LDS, 16B per lane; LDS dest = uniform base + lane*16
#define GLL(gptr, lptr) \
    __builtin_amdgcn_global_load_lds( \
        (const __attribute__((address_space(1))) void*)(gptr), \
        (__attribute__((address_space(3))) void*)(lptr), 16, 0, 0)

// ---------------------------------------------------------------------------
// Prep: E -> E_hi/E_lo (bf16 split) + |e|^2 per code
// ---------------------------------------------------------------------------
__global__ void vq_prep(const float* __restrict__ E, float* __restrict__ enorm,
                        unsigned short* __restrict__ Ehi, unsigned short* __restrict__ Elo) {
    int k = blockIdx.x;      // code
    int lane = threadIdx.x;  // 0..63
    const float4 v = *(const float4*)(E + (size_t)k * DIM + lane * 4);
    float s = v.x * v.x + v.y * v.y + v.z * v.z + v.w * v.w;
    float f[4] = {v.x, v.y, v.z, v.w};
    ushort4 hv, lv;
    unsigned short h;
    h = f2bf(f[0]); hv.x = h; lv.x = f2bf(f[0] - bf2f(h));
    h = f2bf(f[1]); hv.y = h; lv.y = f2bf(f[1] - bf2f(h));
    h = f2bf(f[2]); hv.z = h; lv.z = f2bf(f[2] - bf2f(h));
    h = f2bf(f[3]); hv.w = h; lv.w = f2bf(f[3] - bf2f(h));
    *(ushort4*)(Ehi + (size_t)k * DIM + lane * 4) = hv;
    *(ushort4*)(Elo + (size_t)k * DIM + lane * 4) = lv;
    s += __shfl_down(s, 32);
    s += __shfl_down(s, 16);
    s += __shfl_down(s, 8);
    s += __shfl_down(s, 4);
    s += __shfl_down(s, 2);
    s += __shfl_down(s, 1);
    if (lane == 0) enorm[k] = s;
}

// ---------------------------------------------------------------------------
// Main: MFMA distances + per-row argmin (best + second-best margin)
//   block = 512 thr (8 waves), 128 rows/block (16 rows/wave), grid = 512
//   Per-wave A-state is 64 VGPRs (ahi[8]+alo[8]) -> no scratch spill
//   (previous 4-wave/32-row version spilled 256 B/thread: 33 MB WRITE_SIZE,
//   scratch reloads on the MFMA critical path -> 261 us).
//   Waves 0..3 stage Ehi k-ranges, waves 4..7 stage Elo (2 GLL each / tile).
// ---------------------------------------------------------------------------
__global__ __launch_bounds__(512, 4) void vq_main(
    const float* __restrict__ X,
    const unsigned short* __restrict__ Ehi, const unsigned short* __restrict__ Elo,
    const float* __restrict__ enorm,
    int* __restrict__ rowidx, int* __restrict__ cnt, int* __restrict__ list) {

    // per buffer: hi 8 ksteps x 64 lanes x 8 bf16 = 4096 ushort, lo same
    __shared__ unsigned short Eb[2][8192];   // 32768 B
    __shared__ float EsL[CODES];             // 4096 B

    const int tid  = threadIdx.x;
    const int lane = tid & 63;
    const int w    = tid >> 6;               // wave 0..7
    const int wk   = w & 3;                  // k-range group within hi/lo
    const int isLo = w >> 2;                 // 0: stage Ehi, 1: stage Elo
    const int m    = lane & 15;              // A row-in-16 / C code col
    const int quad = lane >> 4;              // 0..3
    const int row0 = blockIdx.x * 128 + w * 16;

    const unsigned short* __restrict__ Esrc = isLo ? Elo : Ehi;

    // prologue: async-stage tile 0 into buf 0 (in flight during A-frag build)
    {
        const size_t rb0 = (size_t)m * DIM + wk * 32 + quad * 8;
        unsigned short* b0 = &Eb[0][isLo * 4096];
        GLL(Esrc + rb0,       b0 + wk * 512);
        GLL(Esrc + rb0 + 128, b0 + (4 + wk) * 512);
    }

    for (int i = tid; i < CODES; i += 512) EsL[i] = enorm[i];

    // ---- A fragments: 1 row-group x 8 ksteps, hi+lo (64 VGPRs) ----
    bf16x8 ahi[8], alo[8];
    {
        const float* xr = X + (size_t)(row0 + m) * DIM + quad * 8;
        #pragma unroll
        for (int s = 0; s < 8; ++s) {
            float4 p0 = *(const float4*)(xr + s * 32);
            float4 p1 = *(const float4*)(xr + s * 32 + 4);
            float f[8] = {p0.x, p0.y, p0.z, p0.w, p1.x, p1.y, p1.z, p1.w};
            #pragma unroll
            for (int j = 0; j < 8; ++j) {
                unsigned short h = f2bf(f[j]);
                ahi[s][j] = (short)h;
                alo[s][j] = (short)f2bf(f[j] - bf2f(h));
            }
        }
    }

    __syncthreads();   // drains gll (vmcnt0) + EsL writes

    float best[4], sec[4];
    int   bidx[4];
    #pragma unroll
    for (int i = 0; i < 4; ++i) { best[i] = 3.4e38f; sec[i] = 3.4e38f; bidx[i] = 0; }

    for (int t = 0; t < 64; ++t) {
        const int buf = t & 1;
        if (t < 63) {   // async prefetch next tile into other buffer
            const size_t rbn = (size_t)((t + 1) * 16 + m) * DIM + wk * 32 + quad * 8;
            unsigned short* bn = &Eb[buf ^ 1][isLo * 4096];
            GLL(Esrc + rbn,       bn + wk * 512);
            GLL(Esrc + rbn + 128, bn + (4 + wk) * 512);
        }
        // two independent accumulator chains (s<4, s>=4) for MFMA latency
        f32x4 accA = {0.f, 0.f, 0.f, 0.f}, accB = {0.f, 0.f, 0.f, 0.f};
        const unsigned short* b = &Eb[buf][0];
        #pragma unroll
        for (int s = 0; s < 4; ++s) {
            bf16x8 bh = *(const bf16x8*)(b + s * 512 + lane * 8);
            bf16x8 bl = *(const bf16x8*)(b + 4096 + s * 512 + lane * 8);
            accA = __builtin_amdgcn_mfma_f32_16x16x32_bf16(ahi[s], bh, accA, 0, 0, 0);
            accA = __builtin_amdgcn_mfma_f32_16x16x32_bf16(alo[s], bh, accA, 0, 0, 0);
            accA = __builtin_amdgcn_mfma_f32_16x16x32_bf16(ahi[s], bl, accA, 0, 0, 0);
        }
        #pragma unroll
        for (int s = 4; s < 8; ++s) {
            bf16x8 bh = *(const bf16x8*)(b + s * 512 + lane * 8);
            bf16x8 bl = *(const bf16x8*)(b + 4096 + s * 512 + lane * 8);
            accB = __builtin_amdgcn_mfma_f32_16x16x32_bf16(ahi[s], bh, accB, 0, 0, 0);
            accB = __builtin_amdgcn_mfma_f32_16x16x32_bf16(alo[s], bh, accB, 0, 0, 0);
            accB = __builtin_amdgcn_mfma_f32_16x16x32_bf16(ahi[s], bl, accB, 0, 0, 0);
        }
        // C layout: col = lane&15 (code), row = quad*4 + reg
        const float es = EsL[t * 16 + m];
        const int   c  = t * 16 + m;
        #pragma unroll
        for (int r = 0; r < 4; ++r) {
            float d = es - 2.0f * (accA[r] + accB[r]);
            if (d < best[r]) { sec[r] = best[r]; best[r] = d; bidx[r] = c; }
            else if (d < sec[r]) sec[r] = d;
        }
        __syncthreads();   // drains prefetch + protects buf^1 reuse
    }

    // cross-lane argmin reduce over the 16 code-columns (low 4 lane bits)
    #pragma unroll
    for (int i = 0; i < 4; ++i) {
        float b0 = best[i], s0 = sec[i];
        int   i0 = bidx[i];
        #pragma unroll
        for (int msk = 1; msk < 16; msk <<= 1) {
            float ob = __shfl_xor(b0, msk);
            float os = __shfl_xor(s0, msk);
            int   oi = __shfl_xor(i0, msk);
            if (ob < b0 || (ob == b0 && oi < i0)) {
                s0 = fminf(b0, os);
                b0 = ob; i0 = oi;
            } else {
                s0 = fminf(s0, ob);
            }
        }
        best[i] = b0; sec[i] = s0; bidx[i] = i0;
    }
    if (m == 0) {
        #pragma unroll
        for (int r = 0; r < 4; ++r) {
            int grow = row0 + quad * 4 + r;
            rowidx[grow] = bidx[r];
            if (sec[r] - best[r] < TAU) {          // near-tie: exact recheck
                int p = atomicAdd(cnt, 1);
                if (p < BATCH) list[p] = grow;
            }
        }
    }
}

// ---------------------------------------------------------------------------
// Repair v2: exact fp32 argmin for flagged rows.
//   Lanes along k: 64 lanes x float4 = one coalesced code row; butterfly
//   reduce; 4 codes in flight; wave w owns codes [256w, 256w+256).
// ---------------------------------------------------------------------------
__global__ __launch_bounds__(256) void vq_repair(
    const float* __restrict__ X, const float* __restrict__ E,
    const float* __restrict__ enorm,
    int* __restrict__ rowidx, const int* __restrict__ cnt,
    const int* __restrict__ list) {
    __shared__ float wb[4];
    __shared__ int   wi[4];
    int n = *cnt; if (n > BATCH) n = BATCH;
    const int lane = threadIdx.x & 63;
    const int w    = threadIdx.x >> 6;
    for (int i = blockIdx.x; i < n; i += gridDim.x) {
        const int row = list[i];
        const float4 xv = *(const float4*)(X + (size_t)row * DIM + lane * 4);
        float bb = 3.4e38f; int bi = 0;
        for (int j = 0; j < 256; j += 4) {
            const int c = w * 256 + j;
            const float* e0 = E + (size_t)c * DIM + lane * 4;
            float4 v0 = *(const float4*)(e0);
            float4 v1 = *(const float4*)(e0 + DIM);
            float4 v2 = *(const float4*)(e0 + 2 * DIM);
            float4 v3 = *(const float4*)(e0 + 3 * DIM);
            float s0 = xv.x * v0.x + xv.y * v0.y + xv.z * v0.z + xv.w * v0.w;
            float s1 = xv.x * v1.x + xv.y * v1.y + xv.z * v1.z + xv.w * v1.w;
            float s2 = xv.x * v2.x + xv.y * v2.y + xv.z * v2.z + xv.w * v2.w;
            float s3 = xv.x * v3.x + xv.y * v3.y + xv.z * v3.z + xv.w * v3.w;
            #pragma unroll
            for (int msk = 32; msk >= 1; msk >>= 1) {
                s0 += __shfl_xor(s0, msk);
                s1 += __shfl_xor(s1, msk);
                s2 += __shfl_xor(s2, msk);
                s3 += __shfl_xor(s3, msk);
            }
            float d0 = enorm[c]     - 2.0f * s0;
            float d1 = enorm[c + 1] - 2.0f * s1;
            float d2 = enorm[c + 2] - 2.0f * s2;
            float d3 = enorm[c + 3] - 2.0f * s3;
            // c ascending within wave -> strict < keeps lowest index
            if (d0 < bb) { bb = d0; bi = c; }
            if (d1 < bb) { bb = d1; bi = c + 1; }
            if (d2 < bb) { bb = d2; bi = c + 2; }
            if (d3 < bb) { bb = d3; bi = c + 3; }
        }
        if (lane == 0) { wb[w] = bb; wi[w] = bi; }
        __syncthreads();
        if (threadIdx.x == 0) {
            float fb = wb[0]; int fi = wi[0];
            #pragma unroll
            for (int k = 1; k < 4; ++k)
                if (wb[k] < fb || (wb[k] == fb && wi[k] < fi)) { fb = wb[k]; fi = wi[k]; }
            rowidx[row] = fi;
        }
        __syncthreads();
    }
}

// ---------------------------------------------------------------------------
// Epilogue: loss, quantized_st, FULL one-hot rows (zero-fill fused, no memset)
//   1 wave per row; grid = BATCH/4 blocks of 256. All stores nontemporal
//   (streaming, zero reuse).
// ---------------------------------------------------------------------------
__global__ __launch_bounds__(256) void vq_epilogue(
    const float* __restrict__ X, const float* __restrict__ E,
    const int* __restrict__ rowidx,
    float* __restrict__ loss, float* __restrict__ qst, float* __restrict__ onehot) {
    const int lane = threadIdx.x & 63;
    const int w    = threadIdx.x >> 6;
    const int row  = blockIdx.x * 4 + w;
    const int idx  = rowidx[row];
    const size_t xb = (size_t)row * DIM + lane * 4;
    float4 x = *(const float4*)(X + xb);
    float4 q = *(const float4*)(E + (size_t)idx * DIM + lane * 4);
    float4 dl = {q.x - x.x, q.y - x.y, q.z - x.z, q.w - x.w};
    f32x4 lo = {0.25f * dl.x * dl.x, 0.25f * dl.y * dl.y,
                0.25f * dl.z * dl.z, 0.25f * dl.w * dl.w};
    f32x4 qs = {x.x + dl.x, x.y + dl.y, x.z + dl.z, x.w + dl.w};
    __builtin_nontemporal_store(lo, (f32x4*)(loss + xb));
    __builtin_nontemporal_store(qs, (f32x4*)(qst + xb));
    // one-hot: 4 ext-vector nontemporal stores per lane cover the 1024 row
    const size_t ob  = (size_t)row * CODES;
    const int slot = idx >> 2, r3 = idx & 3;
    #pragma unroll
    for (int j = 0; j < 4; ++j) {
        f32x4 z = {0.f, 0.f, 0.f, 0.f};
        if (slot == j * 64 + lane) z[r3] = 1.0f;
        __builtin_nontemporal_store(z, (f32x4*)(onehot + ob + j * 256 + lane * 4));
    }
}

extern "C" void kernel_launch(void* const* d_in, const int* in_sizes, int n_in,
                              void* d_out, int out_size, void* d_ws, size_t ws_size,
                              hipStream_t stream) {
    const float* X = (const float*)d_in[0];   // (65536, 256)
    const float* E = (const float*)d_in[1];   // (1024, 256)
    float* out = (float*)d_out;
    float* loss   = out;
    float* qst    = out + (size_t)BATCH * DIM;
    float* onehot = out + (size_t)2 * BATCH * DIM;

    char* ws = (char*)d_ws;
    float*          enorm  = (float*)ws;                        // 4 KB
    unsigned short* Ehi    = (unsigned short*)(ws + 4096);      // 512 KB
    unsigned short* Elo    = (unsigned short*)(ws + 528384);    // 512 KB
    int*            rowidx = (int*)(ws + 1052672);              // 256 KB
    int*            cnt    = (int*)(ws + 1314816);              // 4 B
    int*            list   = (int*)(ws + 1314880);              // 256 KB

    (void)hipMemsetAsync(cnt, 0, sizeof(int), stream);

    vq_prep<<<CODES, 64, 0, stream>>>(E, enorm, Ehi, Elo);
    vq_main<<<BATCH / 128, 512, 0, stream>>>(X, Ehi, Elo, enorm, rowidx, cnt, list);
    vq_repair<<<2048, 256, 0, stream>>>(X, E, enorm, rowidx, cnt, list);
    vq_epilogue<<<BATCH / 4, 256, 0, stream>>>(X, E, rowidx, loss, qst, onehot);
}